// Round 6
// baseline (722.065 us; speedup 1.0000x reference)
//
#include <hip/hip_runtime.h>

// moment[i] = interval * D[i];  S[i] = sum_{j<i} f[j];  D[i] = sum_{j<i} S[j].
// Segment algebra: state (S,D); appending segment (s, d, n):
//   S' = S + s ;  D' = D + n*S + d
// where s = sum of segment, d = sum of segment-local exclusive shears, n = len.
// f64 accumulation throughout (strictly more accurate than the f32 reference;
// passed validation in R2 with the same numerics).
//
// Single-pass chained scan with decoupled lookback:
//  - tiles assigned by global atomic ticket (safe under undefined dispatch
//    order: a block only waits on tickets already acquired by resident blocks)
//  - per-tile status: flag 0=none, 1=aggregate ready, 2=inclusive prefix ready
//  - all cross-block loads/stores are agent-scope atomics (coherent, no stale L1)
//  - lookback is wave-parallel: 64 predecessors per step, ordered segment
//    reduction via shuffles.
// Tiles staged through LDS with XOR swizzle: global side coalesced (float4,
// lane-consecutive), per-thread-contiguous LDS side bank-conflict-free.

constexpr int BLOCK = 256;
constexpr int ITEMS = 32;                  // elems per thread
constexpr int TILE  = BLOCK * ITEMS;       // 8192 elems per tile
constexpr int NT4   = TILE / 4;            // 2048 float4 entries
constexpr int VPT   = NT4 / BLOCK;         // 8 float4 per thread

// float4-entry swizzle: XOR low 3 bits with bits 3..5. Bijective per 64-entry
// window. Coalesced writes (consecutive e) stay conflict-free; per-thread
// strided reads (e = t*8+jj) spread across all 32 banks.
__device__ __forceinline__ int swz(int e) { return e ^ ((e >> 3) & 7); }

struct Seg { double s, d, n; };
// append R to the right of L
__device__ __forceinline__ Seg seg_combine(const Seg& L, const Seg& R) {
    Seg r; r.s = L.s + R.s; r.d = L.d + R.n * L.s + R.d; r.n = L.n + R.n; return r;
}

__device__ __forceinline__ unsigned flag_load_acq(const unsigned* p) {
    return __hip_atomic_load(p, __ATOMIC_ACQUIRE, __HIP_MEMORY_SCOPE_AGENT);
}
__device__ __forceinline__ void flag_store_rel(unsigned* p, unsigned v) {
    __hip_atomic_store(p, v, __ATOMIC_RELEASE, __HIP_MEMORY_SCOPE_AGENT);
}
__device__ __forceinline__ double val_load(const double* p) {
    unsigned long long u = __hip_atomic_load((const unsigned long long*)p,
                                             __ATOMIC_RELAXED, __HIP_MEMORY_SCOPE_AGENT);
    return __longlong_as_double((long long)u);
}
__device__ __forceinline__ void val_store(double* p, double v) {
    __hip_atomic_store((unsigned long long*)p,
                       (unsigned long long)__double_as_longlong(v),
                       __ATOMIC_RELAXED, __HIP_MEMORY_SCOPE_AGENT);
}

__global__ void k_init(unsigned* __restrict__ cnt, unsigned* __restrict__ flags, int n) {
    int i = blockIdx.x * blockDim.x + threadIdx.x;
    if (i == 0) *cnt = 0u;
    if (i < n) flags[i] = 0u;
}

__global__ __launch_bounds__(BLOCK, 4) void k_scan(
    const float* __restrict__ f, const float* __restrict__ interval,
    float* __restrict__ out,
    unsigned* __restrict__ cnt, unsigned* __restrict__ flags,
    double* __restrict__ aggS, double* __restrict__ aggD,
    double* __restrict__ incS, double* __restrict__ incD)
{
    __shared__ float4 stage[NT4];          // 32 KiB
    __shared__ double ls[BLOCK], ldd[BLOCK];
    __shared__ double bc[2];
    __shared__ unsigned btile;

    const int t = threadIdx.x;
    if (t == 0) btile = atomicAdd(cnt, 1u);   // device-scope ticket
    __syncthreads();
    const int tile = (int)btile;
    const size_t base4 = (size_t)tile * NT4;

    // ---- coalesced load -> swizzled LDS ----
    const float4* g4 = reinterpret_cast<const float4*>(f);
#pragma unroll
    for (int k = 0; k < VPT; ++k) {
        int e = t + k * BLOCK;
        stage[swz(e)] = g4[base4 + e];
    }
    __syncthreads();

    // ---- per-thread local (s,d) over 32 contiguous elems ----
    double s = 0.0, d = 0.0;
#pragma unroll
    for (int jj = 0; jj < VPT; ++jj) {
        float4 v = stage[swz(t * VPT + jj)];
        d += s; s += (double)v.x;
        d += s; s += (double)v.y;
        d += s; s += (double)v.z;
        d += s; s += (double)v.w;
    }

    // ---- block Hillis-Steele pair scan (all threads cover ITEMS elems, so
    //      at offset o the right partial always covers exactly o*ITEMS) ----
    ls[t] = s; ldd[t] = d; __syncthreads();
#pragma unroll
    for (int o = 1; o < BLOCK; o <<= 1) {
        double sl = 0.0, dl = 0.0; const bool has = (t >= o);
        if (has) { sl = ls[t - o]; dl = ldd[t - o]; }
        __syncthreads();
        if (has) { d = dl + (double)(o * ITEMS) * sl + d; s = sl + s; }
        ls[t] = s; ldd[t] = d; __syncthreads();
    }
    const double se = (t == 0) ? 0.0 : ls[t - 1];
    const double de = (t == 0) ? 0.0 : ldd[t - 1];
    const double st = ls[BLOCK - 1];
    const double dt = ldd[BLOCK - 1];

    // ---- wave 0: publish aggregate, decoupled lookback, publish prefix ----
    if (t < 64) {
        const int lane = t;
        if (lane == 0 && tile > 0) {
            val_store(&aggS[tile], st);
            val_store(&aggD[tile], dt);
            flag_store_rel(&flags[tile], 1u);
        }
        double S0 = 0.0, D0 = 0.0;
        if (tile > 0) {
            Seg carry = {0.0, 0.0, 0.0};
            int j0 = tile - 1;
            bool done = false;
            while (!done) {
                int j = j0 - lane;                       // lane l looks at tile j0-l
                unsigned fl = (j < 0) ? 2u : flag_load_acq(&flags[j]);
                unsigned long long b2 = __ballot(fl == 2u);
                unsigned long long b0 = __ballot(fl == 0u);
                int l2;
                if (b2) {
                    l2 = __ffsll((long long)b2) - 1;     // nearest prefix-ready tile
                    if (b0 & ((1ull << l2) - 1ull)) {    // gap before it -> retry
                        __builtin_amdgcn_s_sleep(1); continue;
                    }
                } else {
                    if (b0) { __builtin_amdgcn_s_sleep(1); continue; }
                    l2 = 64;                             // full window of aggregates
                }
                Seg x;
                if (lane < l2) {
                    x.s = val_load(&aggS[j]); x.d = val_load(&aggD[j]); x.n = (double)TILE;
                } else if (lane == l2 && j >= 0) {
                    x.s = val_load(&incS[j]); x.d = val_load(&incD[j]); x.n = 0.0;
                } else {
                    x.s = 0.0; x.d = 0.0; x.n = 0.0;     // identity (incl. virtual j<0)
                }
                // ordered suffix-combine toward lane 0 (higher lane = further left)
#pragma unroll
                for (int o = 1; o < 64; o <<= 1) {
                    double ys = __shfl_down(x.s, o);
                    double yd = __shfl_down(x.d, o);
                    double yn = __shfl_down(x.n, o);
                    if (lane + o < 64) { Seg L = {ys, yd, yn}; x = seg_combine(L, x); }
                }
                if (l2 < 64) {
                    if (lane == 0) { Seg r = seg_combine(x, carry); S0 = r.s; D0 = r.d; }
                    done = true;                          // l2 wave-uniform -> uniform exit
                } else {
                    if (lane == 0) carry = seg_combine(x, carry);
                    j0 -= 64;
                }
            }
        }
        if (lane == 0) {
            val_store(&incS[tile], S0 + st);
            val_store(&incD[tile], D0 + (double)TILE * S0 + dt);
            flag_store_rel(&flags[tile], 2u);
            bc[0] = S0; bc[1] = D0;
        }
    }
    __syncthreads();

    // ---- emit: results written back in place into LDS, then coalesced store ----
    const double S0 = bc[0], D0 = bc[1];
    const double itv = (double)interval[0];
    double S = S0 + se;
    double D = D0 + (double)(t * ITEMS) * S0 + de;
#pragma unroll
    for (int jj = 0; jj < VPT; ++jj) {
        int e = swz(t * VPT + jj);
        float4 v = stage[e];
        float4 o;
        o.x = (float)(itv * D); D += S; S += (double)v.x;
        o.y = (float)(itv * D); D += S; S += (double)v.y;
        o.z = (float)(itv * D); D += S; S += (double)v.z;
        o.w = (float)(itv * D); D += S; S += (double)v.w;
        stage[e] = o;
    }
    __syncthreads();
    float4* o4 = reinterpret_cast<float4*>(out);
#pragma unroll
    for (int k = 0; k < VPT; ++k) {
        int e = t + k * BLOCK;
        o4[base4 + e] = stage[swz(e)];
    }
}

extern "C" void kernel_launch(void* const* d_in, const int* in_sizes, int n_in,
                              void* d_out, int out_size, void* d_ws, size_t ws_size,
                              hipStream_t stream)
{
    const float* forces   = (const float*)d_in[0];
    // d_in[1] = positions: unused by moment()
    const float* interval = (const float*)d_in[2];
    float* out = (float*)d_out;

    const int P = in_sizes[0];
    const int nblocks = P / TILE;            // 2^25 / 8192 = 4096

    // workspace layout (d_ws is poisoned 0xAA every launch; k_init zeroes
    // the parts that need zeros — cnt + flags; value arrays need no init)
    char* ws = (char*)d_ws;
    unsigned* cnt   = (unsigned*)(ws + 0);
    unsigned* flags = (unsigned*)(ws + 1024);                 // 4096*4 = 16 KiB
    double*   aggS  = (double*)  (ws + 20480);
    double*   aggD  = (double*)  (ws + 20480 + 32768);
    double*   incS  = (double*)  (ws + 20480 + 2 * 32768);
    double*   incD  = (double*)  (ws + 20480 + 3 * 32768);

    hipLaunchKernelGGL(k_init, dim3((nblocks + BLOCK - 1) / BLOCK), dim3(BLOCK), 0, stream,
                       cnt, flags, nblocks);
    hipLaunchKernelGGL(k_scan, dim3(nblocks), dim3(BLOCK), 0, stream,
                       forces, interval, out, cnt, flags, aggS, aggD, incS, incD);
}

// Round 8
// 328.884 us; speedup vs baseline: 2.1955x; 2.1955x over previous
//
#include <hip/hip_runtime.h>

// moment[i] = interval * D[i];  S[i] = sum_{j<i} f[j];  D[i] = sum_{j<i} S[j].
// Segment algebra: state (S,D); appending segment (s, d, n):
//   S' = S + s ;  D' = D + n*S + d
// s = sum of segment, d = sum of segment-local exclusive shears.
// Key identity (K1): d = sum_i (n-1-i) * f_i  — order-independent, so the
// per-tile aggregate needs only a weighted reduction, not a scan.
// f64 accumulation (validated in R2/R6: passes vs f32 reference).
//
// R6 lesson: decoupled lookback costs ~400us in cross-XCD flag-spin on MI355X
// (k_scan 500us @ 5% HBM peak, VALUBusy 2.7%). The single-pass saves only
// ~21us of traffic vs reduce-then-scan. So: 3-pass, no inter-block waiting.

constexpr int BLOCK = 256;
constexpr int ITEMS = 8;                   // elems per thread
constexpr int TILE  = BLOCK * ITEMS;       // 2048 elems per tile
constexpr int NT4   = TILE / 4;            // 512 float4 per tile

struct Agg { double s, d; };

// Block-wide Hillis-Steele pair scan; every thread covers NPT elements.
// Returns this thread's exclusive prefix (se, de). Right-operand element
// count at offset o is exactly o*NPT for all combining threads (t >= o).
template <int NPT>
__device__ __forceinline__ void block_pair_scan(double s, double d,
                                                double& se, double& de)
{
    __shared__ double ls[BLOCK], ldd[BLOCK];
    const int t = threadIdx.x;
    ls[t] = s; ldd[t] = d; __syncthreads();
#pragma unroll
    for (int o = 1; o < BLOCK; o <<= 1) {
        double sl = 0.0, dl = 0.0; const bool has = (t >= o);
        if (has) { sl = ls[t - o]; dl = ldd[t - o]; }
        __syncthreads();
        if (has) { d = dl + (double)(o * NPT) * sl + d; s = sl + s; }
        ls[t] = s; ldd[t] = d; __syncthreads();
    }
    se = (t == 0) ? 0.0 : ls[t - 1];
    de = (t == 0) ? 0.0 : ldd[t - 1];
}

// K1: per-tile (s, d) via weighted streaming reduction. Fully coalesced
// (lane t reads 32 contiguous bytes at base + 32t), no scan needed.
__global__ __launch_bounds__(BLOCK) void k_partial(const float* __restrict__ f,
                                                   Agg* __restrict__ agg)
{
    const int t = threadIdx.x;
    const size_t base4 = (size_t)blockIdx.x * NT4;
    const float4* g4 = reinterpret_cast<const float4*>(f);
    const float4 v0 = g4[base4 + 2 * t];
    const float4 v1 = g4[base4 + 2 * t + 1];

    const double w = (double)(TILE - 1 - ITEMS * t);   // weight of elem 8t
    double s = (double)v0.x + (double)v0.y + (double)v0.z + (double)v0.w
             + (double)v1.x + (double)v1.y + (double)v1.z + (double)v1.w;
    double d = w          * (double)v0.x + (w - 1.0) * (double)v0.y
             + (w - 2.0)  * (double)v0.z + (w - 3.0) * (double)v0.w
             + (w - 4.0)  * (double)v1.x + (w - 5.0) * (double)v1.y
             + (w - 6.0)  * (double)v1.z + (w - 7.0) * (double)v1.w;

    // wave (64-lane) shuffle reduce, then cross-wave via 4-entry LDS
#pragma unroll
    for (int o = 32; o > 0; o >>= 1) {
        s += __shfl_down(s, o);
        d += __shfl_down(d, o);
    }
    __shared__ double ss[4], dd[4];
    const int wid = t >> 6, lane = t & 63;
    if (lane == 0) { ss[wid] = s; dd[wid] = d; }
    __syncthreads();
    if (t == 0) {
        agg[blockIdx.x].s = ss[0] + ss[1] + ss[2] + ss[3];
        agg[blockIdx.x].d = dd[0] + dd[1] + dd[2] + dd[3];
    }
}

// K2: one block converts per-tile totals to exclusive (S, D) offsets in place.
__global__ __launch_bounds__(BLOCK) void k_scan_aggs(Agg* __restrict__ agg, int n)
{
    const int t  = threadIdx.x;
    const int ch = n / BLOCK;                 // 16384/256 = 64 tiles per thread
    const int lo = t * ch;
    double s = 0.0, d = 0.0;
    for (int i = 0; i < ch; ++i) {
        Agg a = agg[lo + i];
        d += (double)TILE * s + a.d;          // uses old s
        s += a.s;
    }
    double se, de;
    block_pair_scan<64 * TILE>(s, d, se, de);
    double S = se, D = de;
    for (int i = 0; i < ch; ++i) {
        Agg a = agg[lo + i];
        agg[lo + i].s = S;
        agg[lo + i].d = D;
        D += (double)TILE * S + a.d;          // uses old S
        S += a.s;
    }
}

// K3: re-read forces, local scan, add tile offset, emit. Coalesced 32 B/lane.
__global__ __launch_bounds__(BLOCK) void k_emit(const float* __restrict__ f,
                                                const Agg* __restrict__ agg,
                                                const float* __restrict__ interval,
                                                float* __restrict__ out)
{
    const int t = threadIdx.x;
    const size_t base4 = (size_t)blockIdx.x * NT4;
    const float4* g4 = reinterpret_cast<const float4*>(f);
    const float4 v0 = g4[base4 + 2 * t];
    const float4 v1 = g4[base4 + 2 * t + 1];

    double s = 0.0, d = 0.0;
    d += s; s += (double)v0.x;
    d += s; s += (double)v0.y;
    d += s; s += (double)v0.z;
    d += s; s += (double)v0.w;
    d += s; s += (double)v1.x;
    d += s; s += (double)v1.y;
    d += s; s += (double)v1.z;
    d += s; s += (double)v1.w;

    double se, de;
    block_pair_scan<ITEMS>(s, d, se, de);

    const Agg off = agg[blockIdx.x];
    double S = off.s + se;
    double D = off.d + (double)(ITEMS * t) * off.s + de;
    const double itv = (double)interval[0];

    float4 o0, o1;
    o0.x = (float)(itv * D); D += S; S += (double)v0.x;
    o0.y = (float)(itv * D); D += S; S += (double)v0.y;
    o0.z = (float)(itv * D); D += S; S += (double)v0.z;
    o0.w = (float)(itv * D); D += S; S += (double)v0.w;
    o1.x = (float)(itv * D); D += S; S += (double)v1.x;
    o1.y = (float)(itv * D); D += S; S += (double)v1.y;
    o1.z = (float)(itv * D); D += S; S += (double)v1.z;
    o1.w = (float)(itv * D); D += S; S += (double)v1.w;

    float4* po = reinterpret_cast<float4*>(out);
    po[base4 + 2 * t]     = o0;
    po[base4 + 2 * t + 1] = o1;
}

extern "C" void kernel_launch(void* const* d_in, const int* in_sizes, int n_in,
                              void* d_out, int out_size, void* d_ws, size_t ws_size,
                              hipStream_t stream)
{
    const float* forces   = (const float*)d_in[0];
    // d_in[1] = positions: unused by moment()
    const float* interval = (const float*)d_in[2];
    float* out = (float*)d_out;

    const int P = in_sizes[0];
    const int nblocks = P / TILE;             // 2^25 / 2048 = 16384

    Agg* agg = (Agg*)d_ws;                    // 16384 * 16 B = 256 KiB scratch

    hipLaunchKernelGGL(k_partial,   dim3(nblocks), dim3(BLOCK), 0, stream, forces, agg);
    hipLaunchKernelGGL(k_scan_aggs, dim3(1),       dim3(BLOCK), 0, stream, agg, nblocks);
    hipLaunchKernelGGL(k_emit,      dim3(nblocks), dim3(BLOCK), 0, stream, forces, agg, interval, out);
}